// Round 6
// baseline (105.205 us; speedup 1.0000x reference)
//
#include <hip/hip_runtime.h>

// MPCM: multi-scale patch contrast measure + per-image mean+3*std threshold.
// f64 interior math (binary output => threshold flips are fatal).
// v6: 64x16 tiles / 512 threads, 53.6KB LDS -> 3 blocks/CU = 24 waves/CU
//     (v5 was 16); one pixel-pair per thread (no j loop); parallel k_thresh.

namespace {

constexpr int H = 512, W = 512, NIMG = 16;
constexpr int TW = 64, TH = 16;          // output tile
constexpr int HALO = 13;                 // max k + k/2 = 9 + 4
constexpr int IR = TH + 2 * HALO + 1;    // 43 integral rows (row 0 = zeros)
constexpr int IC = TW + 2 * HALO + 1;    // 91 integral cols (col 0 = zeros)
constexpr int WI = IC;                   // I stride (doubles, odd -> prefix banking)
constexpr int NT = 512;
constexpr int LS = 82;                   // L stride (doubles, even -> aligned pairs)

struct Smem {
  union alignas(16) {
    double L[(TH + 18) * LS];            // 34*82*8 = 22304 B (LH for K=9)
    double red[16];
  } u;
  double I[IR * WI];                     // 43*91*8 = 31304 B exclusive 2D prefix
};                                       // 53608 B -> 3 blocks/CU (160KiB LDS)

// Contiguous-per-lane 16B LDS load (align 8) -> adjacent-offset ds_read2_b64 / b128.
__device__ __forceinline__ double2 ld2(const double* p) {
  double2 v;
  __builtin_memcpy(&v, p, sizeof(double2));
  return v;
}

// One scale: box means from integral (zeroed outside image) -> pcm -> max into mp[2].
// pcm mapping: row r = tid>>5, cols cc..cc+1 with cc = 2*(tid&31).
template <int K, bool BORDER>
__device__ __forceinline__ void scale_pass(Smem& s, int y0, int x0, double mp[2]) {
  constexpr int R   = K / 2;
  constexpr int LH  = TH + 2 * K;        // L rows
  constexpr int LW  = TW + 2 * K;        // L cols (even)
  constexpr int HPW = LW / 2;            // pairs per L row
  constexpr int NP  = LH * HPW;
  constexpr double inv = 1.0 / (double)(K * K);
  const int tid = threadIdx.x;

  // Box sums via 4 integral corners; 2 consecutive-x outputs per iteration.
  for (int pe = tid; pe < NP; pe += NT) {
    const int yy = pe / HPW;
    const int xx = (pe - yy * HPW) * 2;
    const int li = yy + (HALO - K);                  // local input row of center
    const int lj = xx + (HALO - K) - R;              // left corner col
    const double* Ia = s.I + (li - R) * WI + lj;     // top corner row
    const double* Ib = Ia + K * WI;                  // bottom+1 corner row
    const double2 a0 = ld2(Ia), aK = ld2(Ia + K);
    const double2 b0 = ld2(Ib), bK = ld2(Ib + K);
    const double s0 = (bK.x - aK.x) - (b0.x - a0.x);
    const double s1 = (bK.y - aK.y) - (b0.y - a0.y);
    double2 o;
    if (BORDER) {
      const int gy = y0 - K + yy, gx = x0 - K + xx;
      const bool in0 = ((unsigned)gy < (unsigned)H) & ((unsigned)gx < (unsigned)W);
      const bool in1 = ((unsigned)gy < (unsigned)H) & ((unsigned)(gx + 1) < (unsigned)W);
      o.x = in0 ? s0 * inv : 0.0;
      o.y = in1 ? s1 * inv : 0.0;
    } else {
      o.x = s0 * inv;
      o.y = s1 * inv;
    }
    *(double2*)&s.u.L[yy * LS + xx] = o;             // 16B aligned (LS even, xx even)
  }
  __syncthreads();

  {
    const int r  = tid >> 5;
    const int cc = (tid & 31) * 2;
    const double* up  = &s.u.L[r * LS + cc];         // L row (r+K) - K
    const double* mid = up + K * LS;
    const double* dn  = up + 2 * K * LS;
    const double2 u0 = ld2(up),  uK = ld2(up + K),  u2 = ld2(up + 2 * K);
    const double2 m0 = ld2(mid), mK = ld2(mid + K), m2 = ld2(mid + 2 * K);
    const double2 w0 = ld2(dn),  wK = ld2(dn + K),  w2 = ld2(dn + 2 * K);
    {
      const double c = mK.x;
      const double e0 = c - u0.x, e1 = c - uK.x, e2 = c - u2.x, e3 = c - m0.x;
      const double e4 = c - m2.x, e5 = c - w0.x, e6 = c - wK.x, e7 = c - w2.x;
      const double m = fmin(fmin(e0 * e4, e1 * e5), fmin(e2 * e6, e3 * e7));
      mp[0] = fmax(mp[0], m);
    }
    {
      const double c = mK.y;
      const double e0 = c - u0.y, e1 = c - uK.y, e2 = c - u2.y, e3 = c - m0.y;
      const double e4 = c - m2.y, e5 = c - w0.y, e6 = c - wK.y, e7 = c - w2.y;
      const double m = fmin(fmin(e0 * e4, e1 * e5), fmin(e2 * e6, e3 * e7));
      mp[1] = fmax(mp[1], m);
    }
  }
  __syncthreads();
}

template <bool BORDER>
__device__ __forceinline__ void compute_tile(Smem& s, const float* __restrict__ img,
                                             int y0, int x0, double mp[2]) {
  const int tid = threadIdx.x;
  // Stage input directly as f64 into I interior (zero halo + zero row0/col0).
  for (int e = tid; e < IR * IC; e += NT) {
    const int iy = e / IC, ix = e - iy * IC;
    const int gy = y0 - HALO + iy - 1, gx = x0 - HALO + ix - 1;
    double v = 0.0;
    if (BORDER) {
      if (iy > 0 && ix > 0 && (unsigned)gy < (unsigned)H && (unsigned)gx < (unsigned)W)
        v = (double)img[gy * W + gx];
    } else {
      if (iy > 0 && ix > 0) v = (double)img[gy * W + gx];
    }
    s.I[iy * WI + ix] = v;
  }
  __syncthreads();

  // Row prefix in-place (rows 1..IR-1): 42 lanes of wave 0.
  if (tid < IR - 1) {
    double* p = &s.I[(tid + 1) * WI + 1];
    double run = 0.0;
#pragma unroll
    for (int x = 0; x < IC - 1; ++x) { run += p[x]; p[x] = run; }
  }
  __syncthreads();

  // Col prefix in-place (cols 1..IC-1); lanes on consecutive cols -> conflict-free.
  if (tid < IC - 1) {
    double* p = &s.I[WI + (tid + 1)];
    double run = 0.0;
#pragma unroll
    for (int y = 0; y < IR - 1; ++y) { run += *p; *p = run; p += WI; }
  }
  __syncthreads();

  mp[0] = mp[1] = -1.0e300;
  scale_pass<3, BORDER>(s, y0, x0, mp);
  scale_pass<5, BORDER>(s, y0, x0, mp);
  scale_pass<7, BORDER>(s, y0, x0, mp);
  scale_pass<9, BORDER>(s, y0, x0, mp);
}

// Pass 1: mpcm -> ws cache + per-block (sum, sumsq) via wave shuffles (fixed order)
__global__ __launch_bounds__(NT, 6) void k_stats(const float* __restrict__ in,
                                                 double* __restrict__ partials,
                                                 double* __restrict__ wsmp) {
  __shared__ Smem s;
  const int img = blockIdx.z;
  const int y0 = blockIdx.y * TH, x0 = blockIdx.x * TW;
  const bool border = (blockIdx.x == 0) | (blockIdx.x == gridDim.x - 1) |
                      (blockIdx.y == 0) | (blockIdx.y == gridDim.y - 1);
  double mp[2];
  if (border) compute_tile<true>(s, in + (size_t)img * H * W, y0, x0, mp);
  else        compute_tile<false>(s, in + (size_t)img * H * W, y0, x0, mp);

  const int tid = threadIdx.x;
  if (wsmp != nullptr) {
    const int r = tid >> 5, cc = (tid & 31) * 2;
    double2 v; v.x = mp[0]; v.y = mp[1];
    *(double2*)&wsmp[(size_t)img * H * W + (size_t)(y0 + r) * W + (x0 + cc)] = v;
  }

  double s1 = mp[0] + mp[1];
  double s2 = mp[0] * mp[0] + mp[1] * mp[1];
#pragma unroll
  for (int off = 32; off; off >>= 1) {
    s1 += __shfl_down(s1, off);
    s2 += __shfl_down(s2, off);
  }
  if ((tid & 63) == 0) { s.u.red[tid >> 6] = s1; s.u.red[8 + (tid >> 6)] = s2; }
  __syncthreads();
  if (tid == 0) {
    double S = 0.0, S2 = 0.0;
#pragma unroll
    for (int w = 0; w < NT / 64; ++w) { S += s.u.red[w]; S2 += s.u.red[8 + w]; }
    const int bl = (img * gridDim.y + blockIdx.y) * gridDim.x + blockIdx.x;
    partials[2 * bl]     = S;
    partials[2 * bl + 1] = S2;
  }
}

// Pass 2: per-image reduction (fixed order: lane-strided + shuffle tree) -> th
__global__ void k_thresh(const double* __restrict__ partials, double* __restrict__ th) {
  const int img = blockIdx.x;            // 16 blocks, 64 threads
  const int lane = threadIdx.x;
  const int nb = (H / TH) * (W / TW);    // 256
  double S = 0.0, S2 = 0.0;
  for (int b = lane; b < nb; b += 64) {
    S  += partials[2 * (img * nb + b)];
    S2 += partials[2 * (img * nb + b) + 1];
  }
#pragma unroll
  for (int off = 32; off; off >>= 1) {
    S  += __shfl_down(S, off);
    S2 += __shfl_down(S2, off);
  }
  if (lane == 0) {
    const double N = (double)(H * W);
    const double mean = S / N;
    double var = (S2 - S * S / N) / (N - 1.0);
    if (var < 0.0) var = 0.0;
    th[img] = mean + 3.0 * sqrt(var);
  }
}

// Pass 3a (fast): compare cached mpcm against threshold (memory-bound, vectorized)
__global__ __launch_bounds__(256) void k_out_cached(const double* __restrict__ wsmp,
                                                    const double* __restrict__ th,
                                                    float* __restrict__ out) {
  const int n = NIMG * H * W / 2;
  for (int i = blockIdx.x * 256 + threadIdx.x; i < n; i += gridDim.x * 256) {
    const double t = th[i >> 17];  // 2 px per i; H*W/2 = 2^17
    const double2 v = ((const double2*)wsmp)[i];
    float2 o; o.x = (v.x > t) ? 1.0f : 0.0f; o.y = (v.y > t) ? 1.0f : 0.0f;
    ((float2*)out)[i] = o;
  }
}

// Pass 3b (fallback): recompute identical mpcm, write binary output
__global__ __launch_bounds__(NT, 6) void k_out_full(const float* __restrict__ in,
                                                    const double* __restrict__ th,
                                                    float* __restrict__ out) {
  __shared__ Smem s;
  const int img = blockIdx.z;
  const int y0 = blockIdx.y * TH, x0 = blockIdx.x * TW;
  const bool border = (blockIdx.x == 0) | (blockIdx.x == gridDim.x - 1) |
                      (blockIdx.y == 0) | (blockIdx.y == gridDim.y - 1);
  double mp[2];
  if (border) compute_tile<true>(s, in + (size_t)img * H * W, y0, x0, mp);
  else        compute_tile<false>(s, in + (size_t)img * H * W, y0, x0, mp);
  const double t = th[img];
  const int tid = threadIdx.x;
  const int r = tid >> 5, cc = (tid & 31) * 2;
  float2 o;
  o.x = (mp[0] > t) ? 1.0f : 0.0f;
  o.y = (mp[1] > t) ? 1.0f : 0.0f;
  *(float2*)&out[(size_t)img * H * W + (size_t)(y0 + r) * W + (x0 + cc)] = o;
}

}  // namespace

extern "C" void kernel_launch(void* const* d_in, const int* in_sizes, int n_in,
                              void* d_out, int out_size, void* d_ws, size_t ws_size,
                              hipStream_t stream) {
  const float* in = (const float*)d_in[0];
  float* out = (float*)d_out;

  // ws layout: [0,128)                th (16 doubles)
  //            [4096, 4096+65536)     partials (4096 blocks x {sum,sumsq})
  //            [131072, +33554432)    mpcm cache (optional)
  double* th = (double*)d_ws;
  double* partials = (double*)((char*)d_ws + 4096);
  double* wsmp = (double*)((char*)d_ws + 131072);
  const bool cache = ws_size >= (size_t)131072 + (size_t)NIMG * H * W * 8;

  dim3 grid(W / TW, H / TH, NIMG);  // (8, 32, 16) = 4096 blocks
  k_stats<<<grid, NT, 0, stream>>>(in, partials, cache ? wsmp : nullptr);
  k_thresh<<<NIMG, 64, 0, stream>>>(partials, th);
  if (cache) {
    k_out_cached<<<2048, 256, 0, stream>>>(wsmp, th, out);
  } else {
    k_out_full<<<grid, NT, 0, stream>>>(in, th, out);
  }
}

// Round 7
// 91.082 us; speedup vs baseline: 1.1551x; 1.1551x over previous
//
#include <hip/hip_runtime.h>

// MPCM: multi-scale patch contrast measure + per-image mean+3*std threshold.
// f64 interior math (binary output => threshold flips are fatal).
// v7: 64x32 tile @ 1024 threads -> 2 blocks/CU = 32 waves/CU (max) at v5's
//     best work/px; divisions hoisted out of hot loops (incremental walk);
//     1/K^2 deferred past the pair-min (raw sums in L).

namespace {

constexpr int H = 512, W = 512, NIMG = 16;
constexpr int TW = 64, TH = 32;          // output tile
constexpr int HALO = 13;                 // max k + k/2 = 9 + 4
constexpr int IR = TH + 2 * HALO + 1;    // 59 integral rows (row 0 = zeros)
constexpr int IC = TW + 2 * HALO + 1;    // 91 integral cols (col 0 = zeros)
constexpr int WI = IC;                   // I stride (doubles)
constexpr int NT = 1024;
constexpr int LS = 82;                   // L stride (doubles, even -> aligned pairs)

struct Smem {
  union alignas(16) {
    double L[(TH + 18) * LS];            // 50*82*8 = 32800 B (LH for K=9)
    double red[32];
  } u;
  double I[IR * WI];                     // 59*91*8 = 42952 B exclusive 2D prefix
};                                       // 75752 B -> 2 blocks/CU (160KiB LDS)

// Contiguous-per-lane 16B LDS load (align 8) -> adjacent-offset ds_read2_b64 / b128.
__device__ __forceinline__ double2 ld2(const double* p) {
  double2 v;
  __builtin_memcpy(&v, p, sizeof(double2));
  return v;
}

// One scale: raw box sums from integral (zeroed outside image) -> pcm -> max into mp[2].
// pcm mapping: row r = tid>>5 (0..31), cols cc..cc+1 with cc = 2*(tid&31).
template <int K, bool BORDER>
__device__ __forceinline__ void scale_pass(Smem& s, int y0, int x0, double mp[2]) {
  constexpr int R   = K / 2;
  constexpr int LH  = TH + 2 * K;        // L rows
  constexpr int LW  = TW + 2 * K;        // L cols (even)
  constexpr int HPW = LW / 2;            // pairs per L row
  constexpr int NP  = LH * HPW;
  constexpr int ITERS = (NP + NT - 1) / NT;
  constexpr int DY  = NT / HPW;          // incremental walk (compile-time)
  constexpr int DX  = NT % HPW;
  const int tid = threadIdx.x;

  // Box sums via 4 integral corners; 2 consecutive-x outputs per iteration.
  int yy = tid / HPW;                    // one division per scale
  int xp = tid - yy * HPW;
#pragma unroll
  for (int it = 0; it < ITERS; ++it) {
    if (yy < LH) {
      const int xx = xp * 2;
      const int li = yy + (HALO - K);                // local input row of center
      const int lj = xx + (HALO - K) - R;            // left corner col
      const double* Ia = s.I + (li - R) * WI + lj;   // top corner row
      const double* Ib = Ia + K * WI;                // bottom+1 corner row
      const double2 a0 = ld2(Ia), aK = ld2(Ia + K);
      const double2 b0 = ld2(Ib), bK = ld2(Ib + K);
      const double s0 = (bK.x - aK.x) - (b0.x - a0.x);
      const double s1 = (bK.y - aK.y) - (b0.y - a0.y);
      double2 o;
      if (BORDER) {
        const int gy = y0 - K + yy, gx = x0 - K + xx;
        const bool in0 = ((unsigned)gy < (unsigned)H) & ((unsigned)gx < (unsigned)W);
        const bool in1 = ((unsigned)gy < (unsigned)H) & ((unsigned)(gx + 1) < (unsigned)W);
        o.x = in0 ? s0 : 0.0;
        o.y = in1 ? s1 : 0.0;
      } else {
        o.x = s0;
        o.y = s1;
      }
      *(double2*)&s.u.L[yy * LS + xx] = o;           // 16B aligned (LS even, xx even)
    }
    xp += DX; yy += DY;
    if (xp >= HPW) { xp -= HPW; ++yy; }
  }
  __syncthreads();

  {
    constexpr double inv2 = 1.0 / ((double)K * K * K * K);
    const int r  = tid >> 5;
    const int cc = (tid & 31) * 2;
    const double* up  = &s.u.L[r * LS + cc];         // L row (r+K) - K
    const double* mid = up + K * LS;
    const double* dn  = up + 2 * K * LS;
    const double2 u0 = ld2(up),  uK = ld2(up + K),  u2 = ld2(up + 2 * K);
    const double2 m0 = ld2(mid), mK = ld2(mid + K), m2 = ld2(mid + 2 * K);
    const double2 w0 = ld2(dn),  wK = ld2(dn + K),  w2 = ld2(dn + 2 * K);
    {
      const double c = mK.x;
      const double e0 = c - u0.x, e1 = c - uK.x, e2 = c - u2.x, e3 = c - m0.x;
      const double e4 = c - m2.x, e5 = c - w0.x, e6 = c - wK.x, e7 = c - w2.x;
      const double m = fmin(fmin(e0 * e4, e1 * e5), fmin(e2 * e6, e3 * e7));
      mp[0] = fmax(mp[0], m * inv2);
    }
    {
      const double c = mK.y;
      const double e0 = c - u0.y, e1 = c - uK.y, e2 = c - u2.y, e3 = c - m0.y;
      const double e4 = c - m2.y, e5 = c - w0.y, e6 = c - wK.y, e7 = c - w2.y;
      const double m = fmin(fmin(e0 * e4, e1 * e5), fmin(e2 * e6, e3 * e7));
      mp[1] = fmax(mp[1], m * inv2);
    }
  }
  __syncthreads();
}

template <bool BORDER>
__device__ __forceinline__ void compute_tile(Smem& s, const float* __restrict__ img,
                                             int y0, int x0, double mp[2]) {
  const int tid = threadIdx.x;
  // Stage input directly as f64 into I interior (zero halo + zero row0/col0).
  {
    constexpr int NE = IR * IC;              // 5369
    constexpr int SITERS = (NE + NT - 1) / NT;
    constexpr int DIY = NT / IC, DIX = NT % IC;
    int iy = tid / IC;
    int ix = tid - iy * IC;
#pragma unroll
    for (int it = 0; it < SITERS; ++it) {
      if (iy < IR) {
        const int gy = y0 - HALO + iy - 1, gx = x0 - HALO + ix - 1;
        double v = 0.0;
        if (BORDER) {
          if (iy > 0 && ix > 0 && (unsigned)gy < (unsigned)H && (unsigned)gx < (unsigned)W)
            v = (double)img[gy * W + gx];
        } else {
          if (iy > 0 && ix > 0) v = (double)img[gy * W + gx];
        }
        s.I[iy * WI + ix] = v;
      }
      ix += DIX; iy += DIY;
      if (ix >= IC) { ix -= IC; ++iy; }
    }
  }
  __syncthreads();

  // Row prefix in-place (rows 1..IR-1).
  if (tid < IR - 1) {
    double* p = &s.I[(tid + 1) * WI + 1];
    double run = 0.0;
#pragma unroll
    for (int x = 0; x < IC - 1; ++x) { run += p[x]; p[x] = run; }
  }
  __syncthreads();

  // Col prefix in-place (cols 1..IC-1); lanes on consecutive cols -> conflict-free.
  if (tid < IC - 1) {
    double* p = &s.I[WI + (tid + 1)];
    double run = 0.0;
#pragma unroll
    for (int y = 0; y < IR - 1; ++y) { run += *p; *p = run; p += WI; }
  }
  __syncthreads();

  mp[0] = mp[1] = -1.0e300;
  scale_pass<3, BORDER>(s, y0, x0, mp);
  scale_pass<5, BORDER>(s, y0, x0, mp);
  scale_pass<7, BORDER>(s, y0, x0, mp);
  scale_pass<9, BORDER>(s, y0, x0, mp);
}

// Pass 1: mpcm -> ws cache + per-block (sum, sumsq) via wave shuffles (fixed order)
__global__ __launch_bounds__(NT, 8) void k_stats(const float* __restrict__ in,
                                                 double* __restrict__ partials,
                                                 double* __restrict__ wsmp) {
  __shared__ Smem s;
  const int img = blockIdx.z;
  const int y0 = blockIdx.y * TH, x0 = blockIdx.x * TW;
  const bool border = (blockIdx.x == 0) | (blockIdx.x == gridDim.x - 1) |
                      (blockIdx.y == 0) | (blockIdx.y == gridDim.y - 1);
  double mp[2];
  if (border) compute_tile<true>(s, in + (size_t)img * H * W, y0, x0, mp);
  else        compute_tile<false>(s, in + (size_t)img * H * W, y0, x0, mp);

  const int tid = threadIdx.x;
  const int r = tid >> 5, cc = (tid & 31) * 2;
  if (wsmp != nullptr) {
    double2 v; v.x = mp[0]; v.y = mp[1];
    *(double2*)&wsmp[(size_t)img * H * W + (size_t)(y0 + r) * W + (x0 + cc)] = v;
  }

  double s1 = mp[0] + mp[1];
  double s2 = mp[0] * mp[0] + mp[1] * mp[1];
#pragma unroll
  for (int off = 32; off; off >>= 1) {
    s1 += __shfl_down(s1, off);
    s2 += __shfl_down(s2, off);
  }
  if ((tid & 63) == 0) { s.u.red[tid >> 6] = s1; s.u.red[16 + (tid >> 6)] = s2; }
  __syncthreads();
  if (tid == 0) {
    double S = 0.0, S2 = 0.0;
#pragma unroll
    for (int w = 0; w < NT / 64; ++w) { S += s.u.red[w]; S2 += s.u.red[16 + w]; }
    const int bl = (img * gridDim.y + blockIdx.y) * gridDim.x + blockIdx.x;
    partials[2 * bl]     = S;
    partials[2 * bl + 1] = S2;
  }
}

// Pass 2: per-image reduction (fixed order: lane-strided + shuffle tree) -> th
__global__ void k_thresh(const double* __restrict__ partials, double* __restrict__ th) {
  const int img = blockIdx.x;            // 16 blocks, 64 threads
  const int lane = threadIdx.x;
  const int nb = (H / TH) * (W / TW);    // 128
  double S = 0.0, S2 = 0.0;
  for (int b = lane; b < nb; b += 64) {
    S  += partials[2 * (img * nb + b)];
    S2 += partials[2 * (img * nb + b) + 1];
  }
#pragma unroll
  for (int off = 32; off; off >>= 1) {
    S  += __shfl_down(S, off);
    S2 += __shfl_down(S2, off);
  }
  if (lane == 0) {
    const double N = (double)(H * W);
    const double mean = S / N;
    double var = (S2 - S * S / N) / (N - 1.0);
    if (var < 0.0) var = 0.0;
    th[img] = mean + 3.0 * sqrt(var);
  }
}

// Pass 3a (fast): compare cached mpcm against threshold (memory-bound, vectorized)
__global__ __launch_bounds__(256) void k_out_cached(const double* __restrict__ wsmp,
                                                    const double* __restrict__ th,
                                                    float* __restrict__ out) {
  const int n = NIMG * H * W / 2;
  for (int i = blockIdx.x * 256 + threadIdx.x; i < n; i += gridDim.x * 256) {
    const double t = th[i >> 17];  // 2 px per i; H*W/2 = 2^17
    const double2 v = ((const double2*)wsmp)[i];
    float2 o; o.x = (v.x > t) ? 1.0f : 0.0f; o.y = (v.y > t) ? 1.0f : 0.0f;
    ((float2*)out)[i] = o;
  }
}

// Pass 3b (fallback): recompute identical mpcm, write binary output
__global__ __launch_bounds__(NT, 8) void k_out_full(const float* __restrict__ in,
                                                    const double* __restrict__ th,
                                                    float* __restrict__ out) {
  __shared__ Smem s;
  const int img = blockIdx.z;
  const int y0 = blockIdx.y * TH, x0 = blockIdx.x * TW;
  const bool border = (blockIdx.x == 0) | (blockIdx.x == gridDim.x - 1) |
                      (blockIdx.y == 0) | (blockIdx.y == gridDim.y - 1);
  double mp[2];
  if (border) compute_tile<true>(s, in + (size_t)img * H * W, y0, x0, mp);
  else        compute_tile<false>(s, in + (size_t)img * H * W, y0, x0, mp);
  const double t = th[img];
  const int tid = threadIdx.x;
  const int r = tid >> 5, cc = (tid & 31) * 2;
  float2 o;
  o.x = (mp[0] > t) ? 1.0f : 0.0f;
  o.y = (mp[1] > t) ? 1.0f : 0.0f;
  *(float2*)&out[(size_t)img * H * W + (size_t)(y0 + r) * W + (x0 + cc)] = o;
}

}  // namespace

extern "C" void kernel_launch(void* const* d_in, const int* in_sizes, int n_in,
                              void* d_out, int out_size, void* d_ws, size_t ws_size,
                              hipStream_t stream) {
  const float* in = (const float*)d_in[0];
  float* out = (float*)d_out;

  // ws layout: [0,128)                th (16 doubles)
  //            [4096, 4096+32768)     partials (2048 blocks x {sum,sumsq})
  //            [131072, +33554432)    mpcm cache (optional)
  double* th = (double*)d_ws;
  double* partials = (double*)((char*)d_ws + 4096);
  double* wsmp = (double*)((char*)d_ws + 131072);
  const bool cache = ws_size >= (size_t)131072 + (size_t)NIMG * H * W * 8;

  dim3 grid(W / TW, H / TH, NIMG);  // (8, 16, 16) = 2048 blocks
  k_stats<<<grid, NT, 0, stream>>>(in, partials, cache ? wsmp : nullptr);
  k_thresh<<<NIMG, 64, 0, stream>>>(partials, th);
  if (cache) {
    k_out_cached<<<2048, 256, 0, stream>>>(wsmp, th, out);
  } else {
    k_out_full<<<grid, NT, 0, stream>>>(in, th, out);
  }
}